// Round 3
// baseline (96.569 us; speedup 1.0000x reference)
//
#include <hip/hip_runtime.h>
#include <math.h>

#define S_LEN 2048
#define NB 4
#define EMB 1024
#define HD 64
#define NROW (NB * S_LEN)

typedef _Float16 half8 __attribute__((ext_vector_type(8)));
typedef _Float16 half4 __attribute__((ext_vector_type(4)));
typedef float f32x4 __attribute__((ext_vector_type(4)));

static __device__ __forceinline__ f32x4 mfma16(half8 a, half8 b, f32x4 c) {
    return __builtin_amdgcn_mfma_f32_16x16x32_f16(a, b, c, 0, 0, 0);
}

#define NEG_BIG -3.0e38f

// ---------------------------------------------------------------------------
// prep_w: W [1024][64] fp32 -> W^T hi/lo fp16 [192][1024], coalesced via LDS
// transpose.  grid 48 (3 matrices x 16 k-chunks of 64), 256 threads.
// ---------------------------------------------------------------------------
__global__ __launch_bounds__(256) void prep_w(
    const float* __restrict__ Wq, const float* __restrict__ Wk,
    const float* __restrict__ Wv,
    _Float16* __restrict__ wt_h, _Float16* __restrict__ wt_l)
{
    const int g  = blockIdx.x >> 4;
    const int k0 = (blockIdx.x & 15) * 64;
    const float* W = (g == 0) ? Wq : (g == 1) ? Wk : Wv;

    __shared__ float tile[64][68];
    const int t = threadIdx.x;
    {
        const int kk = t >> 2, cb = (t & 3) * 16;
#pragma unroll
        for (int i = 0; i < 4; i++)
            *(f32x4*)&tile[kk][cb + 4 * i] =
                *(const f32x4*)(W + (size_t)(k0 + kk) * HD + cb + 4 * i);
    }
    __syncthreads();
    const int c = t >> 2, kb = (t & 3) * 16;
    half8 h0, h1, l0, l1;
#pragma unroll
    for (int i = 0; i < 16; i++) {
        const float v = tile[kb + i][c];
        const _Float16 h = (_Float16)v;
        const _Float16 l = (_Float16)(v - (float)h);
        if (i < 8) { h0[i] = h; l0[i] = l; }
        else       { h1[i - 8] = h; l1[i - 8] = l; }
    }
    const size_t idx = (size_t)(g * 64 + c) * EMB + k0 + kb;
    *(half8*)(wt_h + idx)     = h0;
    *(half8*)(wt_h + idx + 8) = h1;
    *(half8*)(wt_l + idx)     = l0;
    *(half8*)(wt_l + idx + 8) = l1;
}

// ---------------------------------------------------------------------------
// proj_kernel: fused q,k,v projection, barrier-free streaming MFMA.
// 256 blocks x 512 thr (8 waves).  Block = 32 rows x all 192 cols.
// wave w: kh = w&1 (k-half), ch = (w>>1)&1 (6 col-frags), rh = w>>2 (row-frag).
// A-frags: x fp32 direct from global, split hi/lo in-register.
// B-frags: W^T hi/lo direct from global (L2).  3-term MFMA.
// One barrier: kh-pair reduction through LDS.
// ---------------------------------------------------------------------------
__global__ __launch_bounds__(512) void proj_kernel(
    const float* __restrict__ x,
    const _Float16* __restrict__ wt_h, const _Float16* __restrict__ wt_l,
    const float* __restrict__ bq, const float* __restrict__ bk,
    const float* __restrict__ bv,
    _Float16* __restrict__ qh, _Float16* __restrict__ ql,
    _Float16* __restrict__ kh_, _Float16* __restrict__ kl_,
    _Float16* __restrict__ vt)
{
    const int m0   = blockIdx.x * 32;
    const int t    = threadIdx.x;
    const int lane = t & 63;
    const int w    = t >> 6;
    const int kh = w & 1, ch = (w >> 1) & 1, rh = w >> 2;

    __shared__ float red[4][64][25];

    const int grow = m0 + rh * 16 + (lane & 15);
    const float* xrow = x + (size_t)grow * EMB + kh * 512 + (lane >> 4) * 8;
    const size_t wbase = (size_t)(kh * 512) + (lane >> 4) * 8;

    f32x4 acc[6];
#pragma unroll
    for (int j = 0; j < 6; j++) acc[j] = f32x4{0, 0, 0, 0};

    auto loadA = [&](int st, f32x4& a0, f32x4& a1) {
        const float* p = xrow + st * 32;
        a0 = *(const f32x4*)p;
        a1 = *(const f32x4*)(p + 4);
    };
    auto loadB = [&](int st, half8 (&bh)[6], half8 (&bl)[6]) {
#pragma unroll
        for (int j = 0; j < 6; j++) {
            const int gcol = (ch * 6 + j) * 16 + (lane & 15);
            const size_t off = (size_t)gcol * EMB + wbase + st * 32;
            bh[j] = *(const half8*)(wt_h + off);
            bl[j] = *(const half8*)(wt_l + off);
        }
    };
    auto compute = [&](const f32x4& a0, const f32x4& a1,
                       const half8 (&bh)[6], const half8 (&bl)[6]) {
        half8 axh, axl;
#pragma unroll
        for (int i = 0; i < 4; i++) {
            const _Float16 h = (_Float16)a0[i];
            axh[i] = h; axl[i] = (_Float16)(a0[i] - (float)h);
        }
#pragma unroll
        for (int i = 0; i < 4; i++) {
            const _Float16 h = (_Float16)a1[i];
            axh[4 + i] = h; axl[4 + i] = (_Float16)(a1[i] - (float)h);
        }
#pragma unroll
        for (int j = 0; j < 6; j++) {
            acc[j] = mfma16(axh, bh[j], acc[j]);
            acc[j] = mfma16(axh, bl[j], acc[j]);
            acc[j] = mfma16(axl, bh[j], acc[j]);
        }
    };

    f32x4 a0A, a1A, a0B, a1B;
    half8 bhA[6], blA[6], bhB[6], blB[6];
    loadA(0, a0A, a1A); loadB(0, bhA, blA);
    for (int st = 0; st < 16; st += 2) {
        loadA(st + 1, a0B, a1B); loadB(st + 1, bhB, blB);
        compute(a0A, a1A, bhA, blA);
        if (st + 2 < 16) { loadA(st + 2, a0A, a1A); loadB(st + 2, bhA, blA); }
        compute(a0B, a1B, bhB, blB);
    }

    // ---- kh-pair reduction ----
    const int p = w >> 1;
    if (kh) {
#pragma unroll
        for (int j = 0; j < 6; j++)
#pragma unroll
            for (int r = 0; r < 4; r++) red[p][lane][j * 4 + r] = acc[j][r];
    }
    __syncthreads();
    if (!kh) {
#pragma unroll
        for (int j = 0; j < 6; j++) {
#pragma unroll
            for (int r = 0; r < 4; r++) acc[j][r] += red[p][lane][j * 4 + r];
            const int f = ch * 6 + j, mat = f >> 2, c4 = f & 3;
            const int mcol = c4 * 16 + (lane & 15);
            const float bb = ((mat == 0) ? bq : (mat == 1) ? bk : bv)[mcol];
            const int grow0 = m0 + rh * 16 + (lane >> 4) * 4;
            if (mat == 2) {
                half4 hv;
#pragma unroll
                for (int r = 0; r < 4; r++) hv[r] = (_Float16)(acc[j][r] + bb);
                const int bidx = grow0 >> 11, sr = grow0 & (S_LEN - 1);
                *(half4*)(vt + ((size_t)bidx * HD + mcol) * S_LEN + sr) = hv;
            } else {
                _Float16* oh = (mat == 0) ? qh : kh_;
                _Float16* ol = (mat == 0) ? ql : kl_;
#pragma unroll
                for (int r = 0; r < 4; r++) {
                    const float val = acc[j][r] + bb;
                    const _Float16 h = (_Float16)val;
                    oh[(size_t)(grow0 + r) * HD + mcol] = h;
                    ol[(size_t)(grow0 + r) * HD + mcol] = (_Float16)(val - (float)h);
                }
            }
        }
    }
}

// ---------------------------------------------------------------------------
// attn_kernel: causal flash attention.  512 blocks (qt-major reversed) x
// 512 thr (8 waves).  Block = 16 q-rows; waves split KV tiles (stride 8),
// private (m,l,o), double-buffered K/V prefetch, no barriers in loop.
// 8-way merge via LDS at the end; writes out directly.
// ---------------------------------------------------------------------------
#define SC 11.5415603f /* 8 * log2(e) */

__global__ __launch_bounds__(512) void attn_kernel(
    const _Float16* __restrict__ qh, const _Float16* __restrict__ ql,
    const _Float16* __restrict__ kh_, const _Float16* __restrict__ kl_,
    const _Float16* __restrict__ vt, float* __restrict__ out)
{
    const int id = blockIdx.x;
    const int b  = id & 3;
    const int qt = 127 - (id >> 2);      // biggest blocks dispatched first
    const int q0 = qt * 16;
    const int t    = threadIdx.x;
    const int lane = t & 63;
    const int w    = t >> 6;             // 0..7

    __shared__ __align__(16) _Float16 plds[8][16][40];
    __shared__ __align__(16) float obuf[8][16][68];
    __shared__ float mbuf[8][16], lbuf[8][16];

    const size_t rowq = ((size_t)b * S_LEN + q0 + (lane & 15)) * HD + (lane >> 4) * 8;
    half8 aqh[2], aql[2];
    aqh[0] = *(const half8*)(qh + rowq);
    aqh[1] = *(const half8*)(qh + rowq + 32);
    aql[0] = *(const half8*)(ql + rowq);
    aql[1] = *(const half8*)(ql + rowq + 32);

    f32x4 o[4];
#pragma unroll
    for (int c = 0; c < 4; c++) o[c] = f32x4{0, 0, 0, 0};
    float m_r[4], l_r[4];
#pragma unroll
    for (int r = 0; r < 4; r++) { m_r[r] = NEG_BIG; l_r[r] = 0.f; }

    const int nt = (q0 + 47) >> 5;
    const size_t kbase = (size_t)b * S_LEN * HD;
    const size_t vbase = (size_t)b * HD * S_LEN;

    auto loadT = [&](int kv0, half8 (&vf)[4], half8 (&bh)[4], half8 (&bl)[4]) {
#pragma unroll
        for (int c = 0; c < 4; c++)
            vf[c] = *(const half8*)(vt + vbase +
                     (size_t)(16 * c + (lane & 15)) * S_LEN + kv0 + (lane >> 4) * 8);
#pragma unroll
        for (int f = 0; f < 2; f++) {
            const size_t kr = kbase + (size_t)(kv0 + 16 * f + (lane & 15)) * HD + (lane >> 4) * 8;
            bh[f * 2 + 0] = *(const half8*)(kh_ + kr);
            bh[f * 2 + 1] = *(const half8*)(kh_ + kr + 32);
            bl[f * 2 + 0] = *(const half8*)(kl_ + kr);
            bl[f * 2 + 1] = *(const half8*)(kl_ + kr + 32);
        }
    };

    auto computeT = [&](int kv0, const half8 (&vf)[4],
                        const half8 (&bh)[4], const half8 (&bl)[4]) {
        f32x4 s0 = f32x4{0, 0, 0, 0}, s1 = f32x4{0, 0, 0, 0};
        s0 = mfma16(aqh[0], bh[0], s0);
        s0 = mfma16(aqh[0], bl[0], s0);
        s0 = mfma16(aql[0], bh[0], s0);
        s0 = mfma16(aqh[1], bh[1], s0);
        s0 = mfma16(aqh[1], bl[1], s0);
        s0 = mfma16(aql[1], bh[1], s0);
        s1 = mfma16(aqh[0], bh[2], s1);
        s1 = mfma16(aqh[0], bl[2], s1);
        s1 = mfma16(aql[0], bh[2], s1);
        s1 = mfma16(aqh[1], bh[3], s1);
        s1 = mfma16(aqh[1], bl[3], s1);
        s1 = mfma16(aql[1], bh[3], s1);

        const bool edge = (kv0 + 31 > q0);
        float p0[4], p1[4], corr[4];
#pragma unroll
        for (int r = 0; r < 4; r++) {
            const int qrow = q0 + (lane >> 4) * 4 + r;
            float t0 = s0[r] * SC;
            float t1 = s1[r] * SC;
            if (edge) {
                if (kv0 + (lane & 15) > qrow)      t0 = NEG_BIG;
                if (kv0 + 16 + (lane & 15) > qrow) t1 = NEG_BIG;
            }
            float mt = fmaxf(t0, t1);
#pragma unroll
            for (int msk = 1; msk < 16; msk <<= 1) mt = fmaxf(mt, __shfl_xor(mt, msk));
            const float mn = fmaxf(m_r[r], mt);
            corr[r] = exp2f(m_r[r] - mn);
            m_r[r]  = mn;
            p0[r] = exp2f(t0 - mn);
            p1[r] = exp2f(t1 - mn);
            float rs = p0[r] + p1[r];
#pragma unroll
            for (int msk = 1; msk < 16; msk <<= 1) rs += __shfl_xor(rs, msk);
            l_r[r] = l_r[r] * corr[r] + rs;
        }
#pragma unroll
        for (int c = 0; c < 4; c++)
#pragma unroll
            for (int r = 0; r < 4; r++) o[c][r] *= corr[r];

#pragma unroll
        for (int r = 0; r < 4; r++) {
            const int row = (lane >> 4) * 4 + r;
            plds[w][row][lane & 15]        = (_Float16)p0[r];
            plds[w][row][16 + (lane & 15)] = (_Float16)p1[r];
        }
        const half8 pa = *(const half8*)&plds[w][lane & 15][(lane >> 4) * 8];
#pragma unroll
        for (int c = 0; c < 4; c++) o[c] = mfma16(pa, vf[c], o[c]);
    };

    half8 vfA[4], bhA[4], blA[4], vfB[4], bhB[4], blB[4];
    if (w < nt) loadT(w * 32, vfA, bhA, blA);
    for (int tt = w; tt < nt; tt += 16) {
        const bool h1 = (tt + 8) < nt;
        if (h1) loadT((tt + 8) * 32, vfB, bhB, blB);
        computeT(tt * 32, vfA, bhA, blA);
        if (h1) {
            if (tt + 16 < nt) loadT((tt + 16) * 32, vfA, bhA, blA);
            computeT((tt + 8) * 32, vfB, bhB, blB);
        }
    }

    // ---- 8-way merge ----
    if ((lane & 15) == 0) {
#pragma unroll
        for (int r = 0; r < 4; r++) {
            const int row = (lane >> 4) * 4 + r;
            mbuf[w][row] = m_r[r];
            lbuf[w][row] = l_r[r];
        }
    }
#pragma unroll
    for (int c = 0; c < 4; c++)
#pragma unroll
        for (int r = 0; r < 4; r++)
            obuf[w][(lane >> 4) * 4 + r][16 * c + (lane & 15)] = o[c][r];
    __syncthreads();

    if (t < 256) {
        const int row = t >> 4;
        const int cb  = (t & 15) * 4;
        float M = NEG_BIG;
#pragma unroll
        for (int w2 = 0; w2 < 8; w2++) M = fmaxf(M, mbuf[w2][row]);
        float L = 0.f;
        f32x4 acc = f32x4{0, 0, 0, 0};
#pragma unroll
        for (int w2 = 0; w2 < 8; w2++) {
            const float e = exp2f(mbuf[w2][row] - M);
            L += lbuf[w2][row] * e;
            const f32x4 ov = *(const f32x4*)&obuf[w2][row][cb];
#pragma unroll
            for (int jj = 0; jj < 4; jj++) acc[jj] += ov[jj] * e;
        }
        const float inv = 1.0f / L;
        f32x4 res;
#pragma unroll
        for (int jj = 0; jj < 4; jj++) res[jj] = acc[jj] * inv;
        *(f32x4*)(out + ((size_t)b * S_LEN + q0 + row) * HD + cb) = res;
    }
}

extern "C" void kernel_launch(void* const* d_in, const int* in_sizes, int n_in,
                              void* d_out, int out_size, void* d_ws, size_t ws_size,
                              hipStream_t stream) {
    const float* x  = (const float*)d_in[0];
    const float* Wq = (const float*)d_in[1];
    const float* bq = (const float*)d_in[2];
    const float* Wk = (const float*)d_in[3];
    const float* bk = (const float*)d_in[4];
    const float* Wv = (const float*)d_in[5];
    const float* bv = (const float*)d_in[6];
    float* out = (float*)d_out;

    _Float16* ws = (_Float16*)d_ws;
    const size_t nW = (size_t)192 * EMB;
    const size_t n  = (size_t)NROW * HD;
    _Float16* wt_h = ws;
    _Float16* wt_l = wt_h + nW;
    _Float16* qh  = wt_l + nW;
    _Float16* ql  = qh + n;
    _Float16* khb = ql + n;
    _Float16* klb = khb + n;
    _Float16* vt  = klb + n;

    prep_w<<<48, 256, 0, stream>>>(Wq, Wk, Wv, wt_h, wt_l);
    proj_kernel<<<256, 512, 0, stream>>>(
        x, wt_h, wt_l, bq, bk, bv, qh, ql, khb, klb, vt);
    attn_kernel<<<512, 512, 0, stream>>>(qh, ql, khb, klb, vt, out);
}

// Round 4
// 63.354 us; speedup vs baseline: 1.5243x; 1.5243x over previous
//
#include <hip/hip_runtime.h>
#include <math.h>

#define S_LEN 2048
#define NB 4
#define EMB 1024
#define HD 64
#define NROW (NB * S_LEN)
#define NEG_BIG -3.0e38f
#define SC 11.5415603f /* 8 * log2(e) */

typedef _Float16 half8 __attribute__((ext_vector_type(8)));
typedef _Float16 half4 __attribute__((ext_vector_type(4)));
typedef float f32x4 __attribute__((ext_vector_type(4)));

static __device__ __forceinline__ f32x4 mfma32(half8 a, half8 b, f32x4 c) {
    return __builtin_amdgcn_mfma_f32_16x16x32_f16(a, b, c, 0, 0, 0);
}

#if __has_builtin(__builtin_amdgcn_mfma_f32_16x16x16f16)
#define HAVE_MFMA161616 1
static __device__ __forceinline__ f32x4 mfma16(half4 a, half4 b, f32x4 c) {
    return __builtin_amdgcn_mfma_f32_16x16x16f16(a, b, c, 0, 0, 0);
}
#else
#define HAVE_MFMA161616 0
#endif

// ---------------------------------------------------------------------------
// prep_w: W [1024][64] fp32 -> W^T fp16 (hi only) [192][1024], coalesced.
// grid 48 (3 mats x 16 k-chunks of 64), 256 thr.
// ---------------------------------------------------------------------------
__global__ __launch_bounds__(256) void prep_w(
    const float* __restrict__ Wq, const float* __restrict__ Wk,
    const float* __restrict__ Wv, _Float16* __restrict__ wt_h)
{
    const int g  = blockIdx.x >> 4;
    const int k0 = (blockIdx.x & 15) * 64;
    const float* W = (g == 0) ? Wq : (g == 1) ? Wk : Wv;

    __shared__ float tile[64][68];
    const int t = threadIdx.x;
    {
        const int kk = t >> 2, cb = (t & 3) * 16;
#pragma unroll
        for (int i = 0; i < 4; i++)
            *(f32x4*)&tile[kk][cb + 4 * i] =
                *(const f32x4*)(W + (size_t)(k0 + kk) * HD + cb + 4 * i);
    }
    __syncthreads();
    const int c = t >> 2, kb = (t & 3) * 16;
    half8 h0, h1;
#pragma unroll
    for (int i = 0; i < 16; i++) {
        const _Float16 h = (_Float16)tile[kb + i][c];
        if (i < 8) h0[i] = h; else h1[i - 8] = h;
    }
    const size_t idx = (size_t)(g * 64 + c) * EMB + k0 + kb;
    *(half8*)(wt_h + idx)     = h0;
    *(half8*)(wt_h + idx + 8) = h1;
}

// ---------------------------------------------------------------------------
// proj_kernel: fused q,k,v projection.  256 blocks x 512 thr (8 waves).
// Block = 32 rows x 192 cols; wave w: rowfrag rh=w&1, colgroup cg=w>>1
// (3 colfrags of 16).  BK=64, 16 steps.  W^T hi staged in LDS (dbuf,
// stride-72 pad, reg-staged); x direct global->reg, split hi/lo in-reg.
// 2-term MFMA: (xh + xl) * Wh.  One barrier per step.
// Outputs: qs (fp16, pre-scaled by SC), k hi/lo, v as V^T [4][64][2048].
// ---------------------------------------------------------------------------
__global__ __launch_bounds__(512) void proj_kernel(
    const float* __restrict__ x, const _Float16* __restrict__ wt_h,
    const float* __restrict__ bq, const float* __restrict__ bk,
    const float* __restrict__ bv,
    _Float16* __restrict__ qs, _Float16* __restrict__ kh_,
    _Float16* __restrict__ kl_, _Float16* __restrict__ vt)
{
    const int m0   = blockIdx.x * 32;
    const int t    = threadIdx.x;
    const int lane = t & 63;
    const int w    = t >> 6;
    const int rh = w & 1, cg = w >> 1;

    __shared__ __align__(16) _Float16 wlds[2][192][72];

    f32x4 acc[3];
#pragma unroll
    for (int j = 0; j < 3; j++) acc[j] = f32x4{0, 0, 0, 0};

    const float* xbase = x + (size_t)(m0 + rh * 16 + (lane & 15)) * EMB + (lane >> 4) * 8;

    auto loadW = [&](int st, half8 (&sw)[3]) {
#pragma unroll
        for (int j = 0; j < 3; j++) {
            const int c = t + 512 * j, gcol = c >> 3, koff = (c & 7) * 8;
            sw[j] = *(const half8*)(wt_h + (size_t)gcol * EMB + st * 64 + koff);
        }
    };
    auto writeW = [&](int buf, half8 (&sw)[3]) {
#pragma unroll
        for (int j = 0; j < 3; j++) {
            const int c = t + 512 * j, gcol = c >> 3, koff = (c & 7) * 8;
            *(half8*)&wlds[buf][gcol][koff] = sw[j];
        }
    };
    auto loadX = [&](int st, f32x4 (&xr)[4]) {
        const float* p = xbase + st * 64;
#pragma unroll
        for (int ch = 0; ch < 2; ch++) {
            xr[2 * ch]     = *(const f32x4*)(p + ch * 32);
            xr[2 * ch + 1] = *(const f32x4*)(p + ch * 32 + 4);
        }
    };

    half8 sw[3];
    f32x4 xcur[4], xnxt[4];
    loadW(0, sw);
    loadX(0, xcur);
    writeW(0, sw);
    loadW(1, sw);
    __syncthreads();

    for (int st = 0; st < 16; st++) {
        const int buf = st & 1;
        if (st + 1 < 16) loadX(st + 1, xnxt);

        half8 axh[2], axl[2];
#pragma unroll
        for (int ch = 0; ch < 2; ch++) {
#pragma unroll
            for (int u = 0; u < 4; u++) {
                const float v0 = xcur[2 * ch][u], v1 = xcur[2 * ch + 1][u];
                const _Float16 h0 = (_Float16)v0, h1 = (_Float16)v1;
                axh[ch][u]     = h0;
                axh[ch][4 + u] = h1;
                axl[ch][u]     = (_Float16)(v0 - (float)h0);
                axl[ch][4 + u] = (_Float16)(v1 - (float)h1);
            }
        }
#pragma unroll
        for (int j = 0; j < 3; j++) {
            const int gcol = (cg * 3 + j) * 16 + (lane & 15);
#pragma unroll
            for (int ch = 0; ch < 2; ch++) {
                const half8 bw = *(const half8*)&wlds[buf][gcol][ch * 32 + (lane >> 4) * 8];
                acc[j] = mfma32(axh[ch], bw, acc[j]);
                acc[j] = mfma32(axl[ch], bw, acc[j]);
            }
        }
        if (st + 1 < 16) {
            writeW(buf ^ 1, sw);
            if (st + 2 < 16) loadW(st + 2, sw);
        }
        __syncthreads();
#pragma unroll
        for (int u = 0; u < 4; u++) xcur[u] = xnxt[u];
    }

    // ---- epilogue ----
#pragma unroll
    for (int j = 0; j < 3; j++) {
        const int f = cg * 3 + j, mat = f >> 2, c4 = f & 3;
        const int mcol = c4 * 16 + (lane & 15);
        const float bb = ((mat == 0) ? bq : (mat == 1) ? bk : bv)[mcol];
        const int grow0 = m0 + rh * 16 + (lane >> 4) * 4;
        if (mat == 0) {
#pragma unroll
            for (int r = 0; r < 4; r++)
                qs[(size_t)(grow0 + r) * HD + mcol] = (_Float16)((acc[j][r] + bb) * SC);
        } else if (mat == 1) {
#pragma unroll
            for (int r = 0; r < 4; r++) {
                const float val = acc[j][r] + bb;
                const _Float16 h = (_Float16)val;
                kh_[(size_t)(grow0 + r) * HD + mcol] = h;
                kl_[(size_t)(grow0 + r) * HD + mcol] = (_Float16)(val - (float)h);
            }
        } else {
            half4 hv;
#pragma unroll
            for (int r = 0; r < 4; r++) hv[r] = (_Float16)(acc[j][r] + bb);
            const int bidx = grow0 >> 11, sr = grow0 & (S_LEN - 1);
            *(half4*)(vt + ((size_t)bidx * HD + mcol) * S_LEN + sr) = hv;
        }
    }
}

// ---------------------------------------------------------------------------
// attn_kernel: causal flash attention, swapped-QK layout.
// 512 blocks x 512 thr (8 waves).  Block = 16 q-rows; waves split KV tiles
// (stride 8) with private (m,l,o); reg-dbuf K prefetch; no barriers in loop.
// QK^T computed as mfma(K, Q) -> each lane holds q-row (lane&15), 8 keys.
// Softmax per-lane; P feeds PV directly via mfma_f32_16x16x16f16.
// ---------------------------------------------------------------------------
__global__ __launch_bounds__(512) void attn_kernel(
    const _Float16* __restrict__ qs, const _Float16* __restrict__ kh_,
    const _Float16* __restrict__ kl_, const _Float16* __restrict__ vt,
    float* __restrict__ out)
{
    const int id = blockIdx.x;
    const int b  = id & 3;
    const int qt = 127 - (id >> 2);      // biggest blocks dispatched first
    const int q0 = qt * 16;
    const int t    = threadIdx.x;
    const int lane = t & 63;
    const int w    = t >> 6;             // 0..7

    __shared__ __align__(16) float obuf[8][16][68];
    __shared__ float mbuf[8][16], lbuf[8][16];
#if !HAVE_MFMA161616
    __shared__ __align__(16) _Float16 plds[8][16][40];
#endif

    const size_t rowq = ((size_t)b * S_LEN + q0 + (lane & 15)) * HD + (lane >> 4) * 8;
    const half8 bq0 = *(const half8*)(qs + rowq);
    const half8 bq1 = *(const half8*)(qs + rowq + 32);

    f32x4 o[4];
#pragma unroll
    for (int c = 0; c < 4; c++) o[c] = f32x4{0, 0, 0, 0};
    float m_r = NEG_BIG, l_r = 0.f;

    const int nt = (q0 + 47) >> 5;
    const size_t kbase = (size_t)b * S_LEN * HD;
    const size_t vbase = (size_t)b * HD * S_LEN;

    auto loadK = [&](int kv0, half8 (&kf)[8]) {
#pragma unroll
        for (int h = 0; h < 2; h++) {
            const size_t kr = kbase + (size_t)(kv0 + 16 * h + (lane & 15)) * HD + (lane >> 4) * 8;
            kf[h * 4 + 0] = *(const half8*)(kh_ + kr);
            kf[h * 4 + 1] = *(const half8*)(kh_ + kr + 32);
            kf[h * 4 + 2] = *(const half8*)(kl_ + kr);
            kf[h * 4 + 3] = *(const half8*)(kl_ + kr + 32);
        }
    };
    auto loadV = [&](int kv0, half4 (&vf)[8]) {
#pragma unroll
        for (int c = 0; c < 4; c++)
#pragma unroll
            for (int h = 0; h < 2; h++)
                vf[c * 2 + h] = *(const half4*)(vt + vbase +
                    (size_t)(16 * c + (lane & 15)) * S_LEN + kv0 + 16 * h + (lane >> 4) * 4);
    };

    auto computeT = [&](int kv0, const half8 (&kf)[8], const half4 (&vf)[8]) {
        f32x4 s[2];
#pragma unroll
        for (int h = 0; h < 2; h++) {
            f32x4 s0 = f32x4{0, 0, 0, 0}, s1 = f32x4{0, 0, 0, 0};
            s0 = mfma32(kf[h * 4 + 0], bq0, s0);
            s0 = mfma32(kf[h * 4 + 2], bq0, s0);
            s1 = mfma32(kf[h * 4 + 1], bq1, s1);
            s1 = mfma32(kf[h * 4 + 3], bq1, s1);
            s[h] = s0 + s1;
        }
        const int qrow = q0 + (lane & 15);
        const int kb0  = kv0 + (lane >> 4) * 4;
        float tv[8];
#pragma unroll
        for (int h = 0; h < 2; h++)
#pragma unroll
            for (int r = 0; r < 4; r++)
                tv[h * 4 + r] = (kb0 + 16 * h + r <= qrow) ? s[h][r] : NEG_BIG;

        float mt = tv[0];
#pragma unroll
        for (int i = 1; i < 8; i++) mt = fmaxf(mt, tv[i]);
        mt = fmaxf(mt, __shfl_xor(mt, 16));
        mt = fmaxf(mt, __shfl_xor(mt, 32));
        const float mn = fmaxf(m_r, mt);
        const float corr = exp2f(m_r - mn);
        m_r = mn;

        float p[8], rs = 0.f;
#pragma unroll
        for (int i = 0; i < 8; i++) { p[i] = exp2f(tv[i] - mn); rs += p[i]; }
        rs += __shfl_xor(rs, 16);
        rs += __shfl_xor(rs, 32);
        l_r = l_r * corr + rs;

        float corrB[4];
#pragma unroll
        for (int r = 0; r < 4; r++) corrB[r] = __shfl(corr, (lane >> 4) * 4 + r);
#pragma unroll
        for (int c = 0; c < 4; c++)
#pragma unroll
            for (int r = 0; r < 4; r++) o[c][r] *= corrB[r];

#if HAVE_MFMA161616
        half4 pa[2];
#pragma unroll
        for (int h = 0; h < 2; h++)
#pragma unroll
            for (int r = 0; r < 4; r++) pa[h][r] = (_Float16)p[h * 4 + r];
#pragma unroll
        for (int c = 0; c < 4; c++) {
            o[c] = mfma16(pa[0], vf[c * 2 + 0], o[c]);
            o[c] = mfma16(pa[1], vf[c * 2 + 1], o[c]);
        }
#else
        // fallback: P via wave-private LDS, PV with 16x16x32
#pragma unroll
        for (int h = 0; h < 2; h++)
#pragma unroll
            for (int r = 0; r < 4; r++)
                plds[w][lane & 15][16 * h + (lane >> 4) * 4 + r] = (_Float16)p[h * 4 + r];
        const half8 pa8 = *(const half8*)&plds[w][lane & 15][(lane >> 4) * 8];
#pragma unroll
        for (int c = 0; c < 4; c++) {
            half8 vv;
#pragma unroll
            for (int u = 0; u < 4; u++) { vv[u] = vf[c * 2][u]; vv[4 + u] = vf[c * 2 + 1][u]; }
            // NOTE: fallback path keeps old key ordering; only used if builtin missing
            o[c] = mfma32(pa8, vv, o[c]);
        }
#endif
    };

    half8 kA[8], kB[8];
    half4 vA[8];
    int tile = w;
    if (tile < nt) loadK(tile * 32, kA);
    while (tile < nt) {
        loadV(tile * 32, vA);
        if (tile + 8 < nt) loadK((tile + 8) * 32, kB);
        computeT(tile * 32, kA, vA);
        tile += 8;
        if (tile < nt) {
            loadV(tile * 32, vA);
            if (tile + 8 < nt) loadK((tile + 8) * 32, kA);
            computeT(tile * 32, kB, vA);
            tile += 8;
        }
    }

    // ---- 8-way merge ----
    if (lane < 16) { mbuf[w][lane] = m_r; lbuf[w][lane] = l_r; }
#pragma unroll
    for (int c = 0; c < 4; c++)
#pragma unroll
        for (int r = 0; r < 4; r++)
            obuf[w][(lane >> 4) * 4 + r][16 * c + (lane & 15)] = o[c][r];
    __syncthreads();

    if (t < 256) {
        const int row = t >> 4;
        const int cb  = (t & 15) * 4;
        float M = NEG_BIG;
#pragma unroll
        for (int w2 = 0; w2 < 8; w2++) M = fmaxf(M, mbuf[w2][row]);
        float L = 0.f;
        f32x4 acc = f32x4{0, 0, 0, 0};
#pragma unroll
        for (int w2 = 0; w2 < 8; w2++) {
            const float e = exp2f(mbuf[w2][row] - M);
            L += lbuf[w2][row] * e;
            const f32x4 ov = *(const f32x4*)&obuf[w2][row][cb];
#pragma unroll
            for (int jj = 0; jj < 4; jj++) acc[jj] += ov[jj] * e;
        }
        const float inv = 1.0f / L;
        f32x4 res;
#pragma unroll
        for (int jj = 0; jj < 4; jj++) res[jj] = acc[jj] * inv;
        *(f32x4*)(out + ((size_t)b * S_LEN + q0 + row) * HD + cb) = res;
    }
}

extern "C" void kernel_launch(void* const* d_in, const int* in_sizes, int n_in,
                              void* d_out, int out_size, void* d_ws, size_t ws_size,
                              hipStream_t stream) {
    const float* x  = (const float*)d_in[0];
    const float* Wq = (const float*)d_in[1];
    const float* bq = (const float*)d_in[2];
    const float* Wk = (const float*)d_in[3];
    const float* bk = (const float*)d_in[4];
    const float* Wv = (const float*)d_in[5];
    const float* bv = (const float*)d_in[6];
    float* out = (float*)d_out;

    _Float16* ws = (_Float16*)d_ws;
    const size_t nW = (size_t)192 * EMB;     // 196608
    const size_t n  = (size_t)NROW * HD;     // 524288
    _Float16* wt_h = ws;
    _Float16* qs  = wt_h + nW;
    _Float16* khb = qs + n;
    _Float16* klb = khb + n;
    _Float16* vt  = klb + n;

    prep_w<<<48, 256, 0, stream>>>(Wq, Wk, Wv, wt_h);
    proj_kernel<<<NROW / 32, 512, 0, stream>>>(
        x, wt_h, bq, bk, bv, qs, khb, klb, vt);
    attn_kernel<<<512, 512, 0, stream>>>(qs, khb, klb, vt, out);
}

// Round 5
// 58.447 us; speedup vs baseline: 1.6522x; 1.0840x over previous
//
#include <hip/hip_runtime.h>
#include <math.h>

#define S_LEN 2048
#define NB 4
#define EMB 1024
#define HD 64
#define NROW (NB * S_LEN)
#define NEG_BIG -3.0e38f
#define SC 11.5415603f /* 8 * log2(e) */

typedef _Float16 half8 __attribute__((ext_vector_type(8)));
typedef _Float16 half4 __attribute__((ext_vector_type(4)));
typedef float f32x4 __attribute__((ext_vector_type(4)));

static __device__ __forceinline__ f32x4 mfma32(half8 a, half8 b, f32x4 c) {
    return __builtin_amdgcn_mfma_f32_16x16x32_f16(a, b, c, 0, 0, 0);
}
// K=16 shape: A-frag k-index = (lane>>4)*4 + i, matching the swapped-QK score
// quadrant layout exactly (empirically validated in R4: fallback path would
// have produced wrong results; bench passed at absmax 0.0156).
static __device__ __forceinline__ f32x4 mfma16(half4 a, half4 b, f32x4 c) {
    return __builtin_amdgcn_mfma_f32_16x16x16f16(a, b, c, 0, 0, 0);
}

// ---------------------------------------------------------------------------
// prep_w: W [1024][64] fp32 -> W^T fp16 [192][1024], coalesced via LDS
// transpose.  grid 48 (3 mats x 16 k-chunks of 64), 256 thr.
// ---------------------------------------------------------------------------
__global__ __launch_bounds__(256) void prep_w(
    const float* __restrict__ Wq, const float* __restrict__ Wk,
    const float* __restrict__ Wv, _Float16* __restrict__ wt_h)
{
    const int g  = blockIdx.x >> 4;
    const int k0 = (blockIdx.x & 15) * 64;
    const float* W = (g == 0) ? Wq : (g == 1) ? Wk : Wv;

    __shared__ float tile[64][68];
    const int t = threadIdx.x;
    {
        const int kk = t >> 2, cb = (t & 3) * 16;
#pragma unroll
        for (int i = 0; i < 4; i++)
            *(f32x4*)&tile[kk][cb + 4 * i] =
                *(const f32x4*)(W + (size_t)(k0 + kk) * HD + cb + 4 * i);
    }
    __syncthreads();
    const int c = t >> 2, kb = (t & 3) * 16;
    half8 h0, h1;
#pragma unroll
    for (int i = 0; i < 16; i++) {
        const _Float16 h = (_Float16)tile[kb + i][c];
        if (i < 8) h0[i] = h; else h1[i - 8] = h;
    }
    const size_t idx = (size_t)(g * 64 + c) * EMB + k0 + kb;
    *(half8*)(wt_h + idx)     = h0;
    *(half8*)(wt_h + idx + 8) = h1;
}

// ---------------------------------------------------------------------------
// proj_kernel: fused q,k,v projection.  256 blocks x 512 thr (8 waves).
// Block = 32 rows x 192 cols; wave w: rowfrag rh=w&1, colgroup cg=w>>1.
// BK=64, 16 steps.  W^T staged in LDS (dbuf, stride-72, reg-staged);
// x direct global->reg, single fp16 (x-lo dropped: logit-err ~5e-3 log2).
// Outputs: qs (fp16, pre-scaled by SC), kh fp16, v as V^T [4][64][2048].
// ---------------------------------------------------------------------------
__global__ __launch_bounds__(512) void proj_kernel(
    const float* __restrict__ x, const _Float16* __restrict__ wt_h,
    const float* __restrict__ bq, const float* __restrict__ bk,
    const float* __restrict__ bv,
    _Float16* __restrict__ qs, _Float16* __restrict__ kh_,
    _Float16* __restrict__ vt)
{
    const int m0   = blockIdx.x * 32;
    const int t    = threadIdx.x;
    const int lane = t & 63;
    const int w    = t >> 6;
    const int rh = w & 1, cg = w >> 1;

    __shared__ __align__(16) _Float16 wlds[2][192][72];

    f32x4 acc[3];
#pragma unroll
    for (int j = 0; j < 3; j++) acc[j] = f32x4{0, 0, 0, 0};

    const float* xbase = x + (size_t)(m0 + rh * 16 + (lane & 15)) * EMB + (lane >> 4) * 8;

    auto loadW = [&](int st, half8 (&sw)[3]) {
#pragma unroll
        for (int j = 0; j < 3; j++) {
            const int c = t + 512 * j, gcol = c >> 3, koff = (c & 7) * 8;
            sw[j] = *(const half8*)(wt_h + (size_t)gcol * EMB + st * 64 + koff);
        }
    };
    auto writeW = [&](int buf, half8 (&sw)[3]) {
#pragma unroll
        for (int j = 0; j < 3; j++) {
            const int c = t + 512 * j, gcol = c >> 3, koff = (c & 7) * 8;
            *(half8*)&wlds[buf][gcol][koff] = sw[j];
        }
    };
    auto loadX = [&](int st, f32x4 (&xr)[4]) {
        const float* p = xbase + st * 64;
#pragma unroll
        for (int ch = 0; ch < 2; ch++) {
            xr[2 * ch]     = *(const f32x4*)(p + ch * 32);
            xr[2 * ch + 1] = *(const f32x4*)(p + ch * 32 + 4);
        }
    };

    half8 sw[3];
    f32x4 xcur[4], xnxt[4];
    loadW(0, sw);
    loadX(0, xcur);
    writeW(0, sw);
    loadW(1, sw);
    __syncthreads();

    for (int st = 0; st < 16; st++) {
        const int buf = st & 1;
        if (st + 1 < 16) loadX(st + 1, xnxt);

        half8 axh[2];
#pragma unroll
        for (int ch = 0; ch < 2; ch++) {
#pragma unroll
            for (int u = 0; u < 4; u++) {
                axh[ch][u]     = (_Float16)xcur[2 * ch][u];
                axh[ch][4 + u] = (_Float16)xcur[2 * ch + 1][u];
            }
        }
#pragma unroll
        for (int j = 0; j < 3; j++) {
            const int gcol = (cg * 3 + j) * 16 + (lane & 15);
#pragma unroll
            for (int ch = 0; ch < 2; ch++) {
                const half8 bw = *(const half8*)&wlds[buf][gcol][ch * 32 + (lane >> 4) * 8];
                acc[j] = mfma32(axh[ch], bw, acc[j]);
            }
        }
        if (st + 1 < 16) {
            writeW(buf ^ 1, sw);
            if (st + 2 < 16) loadW(st + 2, sw);
        }
        __syncthreads();
#pragma unroll
        for (int u = 0; u < 4; u++) xcur[u] = xnxt[u];
    }

    // ---- epilogue ----
#pragma unroll
    for (int j = 0; j < 3; j++) {
        const int f = cg * 3 + j, mat = f >> 2, c4 = f & 3;
        const int mcol = c4 * 16 + (lane & 15);
        const float bb = ((mat == 0) ? bq : (mat == 1) ? bk : bv)[mcol];
        const int grow0 = m0 + rh * 16 + (lane >> 4) * 4;
        if (mat == 0) {
#pragma unroll
            for (int r = 0; r < 4; r++)
                qs[(size_t)(grow0 + r) * HD + mcol] = (_Float16)((acc[j][r] + bb) * SC);
        } else if (mat == 1) {
#pragma unroll
            for (int r = 0; r < 4; r++)
                kh_[(size_t)(grow0 + r) * HD + mcol] = (_Float16)(acc[j][r] + bb);
        } else {
            half4 hv;
#pragma unroll
            for (int r = 0; r < 4; r++) hv[r] = (_Float16)(acc[j][r] + bb);
            const int bidx = grow0 >> 11, sr = grow0 & (S_LEN - 1);
            *(half4*)(vt + ((size_t)bidx * HD + mcol) * S_LEN + sr) = hv;
        }
    }
}

// ---------------------------------------------------------------------------
// attn_kernel: causal flash attention, swapped-QK layout.
// 512 blocks x 512 thr (8 waves).  Block = 16 q-rows; waves split KV tiles
// (stride 8) with private (m,l,o); reg-dbuf K AND V prefetch; no barriers in
// loop.  QK^T as mfma(K, Q) -> lane holds q-row (lane&15), 8 keys.  Softmax
// per-lane; P feeds PV directly via mfma_f32_16x16x16f16 (K=16 quadrants).
// ---------------------------------------------------------------------------
__global__ __launch_bounds__(512) void attn_kernel(
    const _Float16* __restrict__ qs, const _Float16* __restrict__ kh_,
    const _Float16* __restrict__ vt, float* __restrict__ out)
{
    const int id = blockIdx.x;
    const int b  = id & 3;
    const int qt = 127 - (id >> 2);      // biggest blocks dispatched first
    const int q0 = qt * 16;
    const int t    = threadIdx.x;
    const int lane = t & 63;
    const int w    = t >> 6;             // 0..7

    __shared__ __align__(16) float obuf[8][16][68];
    __shared__ float mbuf[8][16], lbuf[8][16];

    const size_t rowq = ((size_t)b * S_LEN + q0 + (lane & 15)) * HD + (lane >> 4) * 8;
    const half8 bq0 = *(const half8*)(qs + rowq);
    const half8 bq1 = *(const half8*)(qs + rowq + 32);

    f32x4 o[4];
#pragma unroll
    for (int c = 0; c < 4; c++) o[c] = f32x4{0, 0, 0, 0};
    float m_r = NEG_BIG, l_r = 0.f;

    const int nt = (q0 + 47) >> 5;
    const size_t kbase = (size_t)b * S_LEN * HD;
    const size_t vbase = (size_t)b * HD * S_LEN;

    auto loadK = [&](int kv0, half8 (&kf)[4]) {
#pragma unroll
        for (int h = 0; h < 2; h++) {
            const size_t kr = kbase + (size_t)(kv0 + 16 * h + (lane & 15)) * HD + (lane >> 4) * 8;
            kf[h * 2 + 0] = *(const half8*)(kh_ + kr);
            kf[h * 2 + 1] = *(const half8*)(kh_ + kr + 32);
        }
    };
    auto loadV = [&](int kv0, half4 (&vf)[8]) {
#pragma unroll
        for (int c = 0; c < 4; c++)
#pragma unroll
            for (int h = 0; h < 2; h++)
                vf[c * 2 + h] = *(const half4*)(vt + vbase +
                    (size_t)(16 * c + (lane & 15)) * S_LEN + kv0 + 16 * h + (lane >> 4) * 4);
    };

    auto computeT = [&](int kv0, const half8 (&kf)[4], const half4 (&vf)[8]) {
        __builtin_amdgcn_s_setprio(1);
        f32x4 s[2];
#pragma unroll
        for (int h = 0; h < 2; h++) {
            f32x4 a = f32x4{0, 0, 0, 0};
            a = mfma32(kf[h * 2 + 0], bq0, a);
            a = mfma32(kf[h * 2 + 1], bq1, a);
            s[h] = a;
        }
        __builtin_amdgcn_s_setprio(0);

        const int qrow = q0 + (lane & 15);
        const int kb0  = kv0 + (lane >> 4) * 4;
        float tv[8];
#pragma unroll
        for (int h = 0; h < 2; h++)
#pragma unroll
            for (int r = 0; r < 4; r++)
                tv[h * 4 + r] = (kb0 + 16 * h + r <= qrow) ? s[h][r] : NEG_BIG;

        float mt = tv[0];
#pragma unroll
        for (int i = 1; i < 8; i++) mt = fmaxf(mt, tv[i]);
        mt = fmaxf(mt, __shfl_xor(mt, 16));
        mt = fmaxf(mt, __shfl_xor(mt, 32));
        const float mn = fmaxf(m_r, mt);
        const float corr = exp2f(m_r - mn);
        m_r = mn;

        float p[8], rs = 0.f;
#pragma unroll
        for (int i = 0; i < 8; i++) { p[i] = exp2f(tv[i] - mn); rs += p[i]; }
        rs += __shfl_xor(rs, 16);
        rs += __shfl_xor(rs, 32);
        l_r = l_r * corr + rs;

        float corrB[4];
#pragma unroll
        for (int r = 0; r < 4; r++) corrB[r] = __shfl(corr, (lane >> 4) * 4 + r);
#pragma unroll
        for (int c = 0; c < 4; c++)
#pragma unroll
            for (int r = 0; r < 4; r++) o[c][r] *= corrB[r];

        half4 pa[2];
#pragma unroll
        for (int h = 0; h < 2; h++)
#pragma unroll
            for (int r = 0; r < 4; r++) pa[h][r] = (_Float16)p[h * 4 + r];
        __builtin_amdgcn_s_setprio(1);
#pragma unroll
        for (int c = 0; c < 4; c++) {
            o[c] = mfma16(pa[0], vf[c * 2 + 0], o[c]);
            o[c] = mfma16(pa[1], vf[c * 2 + 1], o[c]);
        }
        __builtin_amdgcn_s_setprio(0);
    };

    half8 kA[4], kB[4];
    half4 vA[8], vB[8];
    int tile = w;
    if (tile < nt) { loadK(tile * 32, kA); loadV(tile * 32, vA); }
    while (tile < nt) {
        if (tile + 8 < nt) { loadK((tile + 8) * 32, kB); loadV((tile + 8) * 32, vB); }
        computeT(tile * 32, kA, vA);
        tile += 8;
        if (tile < nt) {
            if (tile + 8 < nt) { loadK((tile + 8) * 32, kA); loadV((tile + 8) * 32, vA); }
            computeT(tile * 32, kB, vB);
            tile += 8;
        }
    }

    // ---- 8-way merge ----
    if (lane < 16) { mbuf[w][lane] = m_r; lbuf[w][lane] = l_r; }
#pragma unroll
    for (int c = 0; c < 4; c++)
#pragma unroll
        for (int r = 0; r < 4; r++)
            obuf[w][(lane >> 4) * 4 + r][16 * c + (lane & 15)] = o[c][r];
    __syncthreads();

    if (t < 256) {
        const int row = t >> 4;
        const int cb  = (t & 15) * 4;
        float M = NEG_BIG;
#pragma unroll
        for (int w2 = 0; w2 < 8; w2++) M = fmaxf(M, mbuf[w2][row]);
        float L = 0.f;
        f32x4 acc = f32x4{0, 0, 0, 0};
#pragma unroll
        for (int w2 = 0; w2 < 8; w2++) {
            const float e = exp2f(mbuf[w2][row] - M);
            L += lbuf[w2][row] * e;
            const f32x4 ov = *(const f32x4*)&obuf[w2][row][cb];
#pragma unroll
            for (int jj = 0; jj < 4; jj++) acc[jj] += ov[jj] * e;
        }
        const float inv = 1.0f / L;
        f32x4 res;
#pragma unroll
        for (int jj = 0; jj < 4; jj++) res[jj] = acc[jj] * inv;
        *(f32x4*)(out + ((size_t)b * S_LEN + q0 + row) * HD + cb) = res;
    }
}

extern "C" void kernel_launch(void* const* d_in, const int* in_sizes, int n_in,
                              void* d_out, int out_size, void* d_ws, size_t ws_size,
                              hipStream_t stream) {
    const float* x  = (const float*)d_in[0];
    const float* Wq = (const float*)d_in[1];
    const float* bq = (const float*)d_in[2];
    const float* Wk = (const float*)d_in[3];
    const float* bk = (const float*)d_in[4];
    const float* Wv = (const float*)d_in[5];
    const float* bv = (const float*)d_in[6];
    float* out = (float*)d_out;

    _Float16* ws = (_Float16*)d_ws;
    const size_t nW = (size_t)192 * EMB;     // 196608
    const size_t n  = (size_t)NROW * HD;     // 524288
    _Float16* wt_h = ws;
    _Float16* qs  = wt_h + nW;
    _Float16* khb = qs + n;
    _Float16* vt  = khb + n;

    prep_w<<<48, 256, 0, stream>>>(Wq, Wk, Wv, wt_h);
    proj_kernel<<<NROW / 32, 512, 0, stream>>>(
        x, wt_h, bq, bk, bv, qs, khb, vt);
    attn_kernel<<<512, 512, 0, stream>>>(qs, khb, vt, out);
}